// Round 12
// baseline (148.155 us; speedup 1.0000x reference)
//
#include <hip/hip_runtime.h>

// R12 = R10 (best measured, 144.7us) + 8-wide probe.
//  K1 bounds: streaming bin-transition scan of sorted addr2site_map -> eb[2049]
//             (coalesced vec4, no dependent-load chains; reads 24 MB only).
//  K2 mark:   bin g builds its 128-word LDS bitmap from a2s[eb[g]..eb[g+1])
//             where sig>0 (register-merged LDS atomics), then stores its
//             disjoint 512 B slice to the global bitmap. Full coverage ->
//             no zero pass, no global atomics.
//  K3 probe:  index-partitioned, 8 elems/thread, NT streaming loads/stores;
//             ss sorted => a wave's bitmap probes land on 1-2 cachelines.

typedef int   v4i __attribute__((ext_vector_type(4)));
typedef float v4f __attribute__((ext_vector_type(4)));

static constexpr int WORDS_PER_BIN = 128;            // 512 B bitmap slice
static constexpr int SITES_PER_BIN = 4096;           // = 2^BIN_SHIFT
static constexpr int BIN_SHIFT     = 12;
static constexpr int NBINS         = 2048;
static constexpr int BLOCK         = 256;

// ---- K1: boundaries of a2s by bin transitions ------------------------------
__global__ __launch_bounds__(BLOCK) void bounds_kernel(
    const int* __restrict__ a2s, int* __restrict__ eb, int n_clb)
{
    const int t = blockIdx.x * BLOCK + threadIdx.x;
    const int s = t * 4;
    if (s >= n_clb) return;
    int v[4];
    int cnt;
    if (s + 4 <= n_clb) {
        v4i a = __builtin_nontemporal_load((const v4i*)(a2s + s));
        v[0] = a.x; v[1] = a.y; v[2] = a.z; v[3] = a.w;
        cnt = 4;
    } else {
        cnt = n_clb - s;
        for (int j = 0; j < cnt; ++j) v[j] = a2s[s + j];
    }
    int pbin = (s == 0) ? -1 : (a2s[s - 1] >> BIN_SHIFT);  // line is in L1
    for (int j = 0; j < cnt; ++j) {
        const int i = s + j;
        const int cbin = v[j] >> BIN_SHIFT;
        for (int b = pbin + 1; b <= cbin; ++b) eb[b] = i;   // ~1 write / 2929 elems
        if (i == n_clb - 1)
            for (int b = cbin + 1; b <= NBINS; ++b) eb[b] = n_clb;
        pbin = cbin;
    }
}

// ---- K2: per-bin mark -> disjoint global bitmap slice ----------------------
__global__ __launch_bounds__(BLOCK) void mark_kernel(
    const int* __restrict__ sig, const int* __restrict__ a2s,
    const int* __restrict__ eb, unsigned int* __restrict__ bm, int n_clb)
{
    __shared__ unsigned int lbm[WORDS_PER_BIN];

    const int g        = blockIdx.x;
    const int siteBase = g * SITES_PER_BIN;
    const int siteEnd  = siteBase + SITES_PER_BIN;

    if (threadIdx.x < WORDS_PER_BIN) lbm[threadIdx.x] = 0u;
    const int e0 = eb[g], e1 = eb[g + 1];
    __syncthreads();

    // 8 entries/thread (4 NT vec4 loads in flight). Strays outside the bin's
    // site range fail the range check (they belong to neighbor bins).
    const int mstart = e0 & ~3;
    for (int s = mstart + threadIdx.x * 8; s < e1; s += BLOCK * 8) {
        int av[8], gv[8];
        if (s + 8 <= n_clb) {
            v4i a0 = __builtin_nontemporal_load((const v4i*)(a2s + s));
            v4i a1 = __builtin_nontemporal_load((const v4i*)(a2s + s + 4));
            v4i g0 = __builtin_nontemporal_load((const v4i*)(sig + s));
            v4i g1 = __builtin_nontemporal_load((const v4i*)(sig + s + 4));
            av[0]=a0.x; av[1]=a0.y; av[2]=a0.z; av[3]=a0.w;
            av[4]=a1.x; av[5]=a1.y; av[6]=a1.z; av[7]=a1.w;
            gv[0]=g0.x; gv[1]=g0.y; gv[2]=g0.z; gv[3]=g0.w;
            gv[4]=g1.x; gv[5]=g1.y; gv[6]=g1.z; gv[7]=g1.w;
        } else {
#pragma unroll
            for (int j = 0; j < 8; ++j) {
                const int i = s + j;
                const bool ok = i < n_clb;
                av[j] = ok ? a2s[i] : -1;
                gv[j] = ok ? sig[i] : 0;
            }
        }
        unsigned int curw = 0xFFFFFFFFu, curm = 0u;
#pragma unroll
        for (int j = 0; j < 8; ++j) {
            const int site = av[j];
            if (gv[j] > 0 && site >= siteBase && site < siteEnd) {
                const unsigned int u = (unsigned int)(site - siteBase);
                const unsigned int w = u >> 5;
                const unsigned int m = 1u << (u & 31u);
                if (w == curw) curm |= m;
                else { if (curm) atomicOr(&lbm[curw], curm); curw = w; curm = m; }
            }
        }
        if (curm) atomicOr(&lbm[curw], curm);
    }

    __syncthreads();

    // Disjoint 512 B slice -> regular stores (keep it cache-resident for K3).
    if (threadIdx.x < WORDS_PER_BIN / 4)
        ((v4i*)(bm + g * WORDS_PER_BIN))[threadIdx.x] =
            ((const v4i*)lbm)[threadIdx.x];
}

// ---- K3: index-partitioned probe, 8 elems/thread ---------------------------
__global__ __launch_bounds__(BLOCK) void probe_kernel(
    const int* __restrict__ ss, const float* __restrict__ sc,
    const unsigned int* __restrict__ bm,
    float* __restrict__ rem, float* __restrict__ avail, int n8)
{
    const int t = blockIdx.x * BLOCK + threadIdx.x;
    if (t >= n8) return;
    const int base = t * 8;

    v4i s0 = __builtin_nontemporal_load((const v4i*)(ss + base));
    v4i s1 = __builtin_nontemporal_load((const v4i*)(ss + base + 4));
    v4f f0 = __builtin_nontemporal_load((const v4f*)(sc + base));
    v4f f1 = __builtin_nontemporal_load((const v4f*)(sc + base + 4));

    int   sv[8] = {s0.x, s0.y, s0.z, s0.w, s1.x, s1.y, s1.z, s1.w};
    float fv[8] = {f0.x, f0.y, f0.z, f0.w, f1.x, f1.y, f1.z, f1.w};
    float rv[8], av[8];
#pragma unroll
    for (int j = 0; j < 8; ++j) {
        const unsigned int u   = (unsigned int)sv[j];
        const unsigned int bit = (bm[u >> 5] >> (u & 31u)) & 1u;
        rv[j] = bit ? 0.0f : 1.0f;
        av[j] = bit ? 0.0f : fv[j];
    }

    v4f r0 = {rv[0], rv[1], rv[2], rv[3]};
    v4f r1 = {rv[4], rv[5], rv[6], rv[7]};
    v4f a0 = {av[0], av[1], av[2], av[3]};
    v4f a1 = {av[4], av[5], av[6], av[7]};
    __builtin_nontemporal_store(r0, (v4f*)(rem + base));
    __builtin_nontemporal_store(r1, (v4f*)(rem + base + 4));
    __builtin_nontemporal_store(a0, (v4f*)(avail + base));
    __builtin_nontemporal_store(a1, (v4f*)(avail + base + 4));
}

__global__ void probe_tail_kernel(
    const int* __restrict__ ss, const float* __restrict__ sc,
    const unsigned int* __restrict__ bm,
    float* __restrict__ rem, float* __restrict__ avail, int start, int n)
{
    const int i = start + blockIdx.x * blockDim.x + threadIdx.x;
    if (i >= n) return;
    const unsigned int u   = (unsigned int)ss[i];
    const unsigned int bit = (bm[u >> 5] >> (u & 31u)) & 1u;
    rem[i]   = bit ? 0.0f : 1.0f;
    avail[i] = bit ? 0.0f : sc[i];
}

extern "C" void kernel_launch(void* const* d_in, const int* in_sizes, int n_in,
                              void* d_out, int out_size, void* d_ws, size_t ws_size,
                              hipStream_t stream) {
    const int*   ss  = (const int*)d_in[0];
    const int*   sig = (const int*)d_in[1];
    const int*   a2s = (const int*)d_in[2];
    const float* sc  = (const float*)d_in[3];
    const int n_slice = in_sizes[0];
    const int n_clb   = in_sizes[1];

    unsigned int* bm = (unsigned int*)d_ws;                 // 1 MiB bitmap
    int*          eb = (int*)(bm + NBINS * WORDS_PER_BIN);  // 2049 ints

    // K1: boundaries of a2s (24 MB streaming scan)
    const int t1 = (n_clb / 4 + BLOCK - 1) / BLOCK + 1;
    bounds_kernel<<<t1, BLOCK, 0, stream>>>(a2s, eb, n_clb);

    // K2: per-bin mark -> global bitmap (disjoint stores, full coverage)
    mark_kernel<<<NBINS, BLOCK, 0, stream>>>(sig, a2s, eb, bm, n_clb);

    // K3: index-partitioned probe -> outputs
    float* rem   = (float*)d_out;
    float* avail = rem + n_slice;
    const int n8 = n_slice / 8;
    if (n8 > 0)
        probe_kernel<<<(n8 + BLOCK - 1) / BLOCK, BLOCK, 0, stream>>>(
            ss, sc, bm, rem, avail, n8);
    if (n8 * 8 < n_slice)
        probe_tail_kernel<<<1, 64, 0, stream>>>(ss, sc, bm, rem, avail,
                                                n8 * 8, n_slice);
}

// Round 13
// 145.171 us; speedup vs baseline: 1.0206x; 1.0206x over previous
//
#include <hip/hip_runtime.h>

// R13 = exact revert to R10 (best measured, 144.7us).
//  K1 bounds: streaming bin-transition scan of sorted addr2site_map -> eb[2049]
//             (coalesced vec4, no dependent-load chains; reads 24 MB only).
//  K2 mark:   bin g builds its 128-word LDS bitmap from a2s[eb[g]..eb[g+1])
//             where sig>0 (register-merged LDS atomics), then stores its
//             disjoint 512 B slice to the global bitmap. Full coverage ->
//             no zero pass, no global atomics.
//  K3 probe:  index-partitioned, 4 elems/thread (5860 blocks: max TLP),
//             probes cache-resident bitmap, NT streaming loads/stores.

typedef int   v4i __attribute__((ext_vector_type(4)));
typedef float v4f __attribute__((ext_vector_type(4)));

static constexpr int WORDS_PER_BIN = 128;            // 512 B bitmap slice
static constexpr int SITES_PER_BIN = 4096;           // = 2^BIN_SHIFT
static constexpr int BIN_SHIFT     = 12;
static constexpr int NBINS         = 2048;
static constexpr int BLOCK         = 256;

// ---- K1: boundaries of a2s by bin transitions ------------------------------
__global__ __launch_bounds__(BLOCK) void bounds_kernel(
    const int* __restrict__ a2s, int* __restrict__ eb, int n_clb)
{
    const int t = blockIdx.x * BLOCK + threadIdx.x;
    const int s = t * 4;
    if (s >= n_clb) return;
    int v[4];
    int cnt;
    if (s + 4 <= n_clb) {
        v4i a = __builtin_nontemporal_load((const v4i*)(a2s + s));
        v[0] = a.x; v[1] = a.y; v[2] = a.z; v[3] = a.w;
        cnt = 4;
    } else {
        cnt = n_clb - s;
        for (int j = 0; j < cnt; ++j) v[j] = a2s[s + j];
    }
    int pbin = (s == 0) ? -1 : (a2s[s - 1] >> BIN_SHIFT);  // line is in L1
    for (int j = 0; j < cnt; ++j) {
        const int i = s + j;
        const int cbin = v[j] >> BIN_SHIFT;
        for (int b = pbin + 1; b <= cbin; ++b) eb[b] = i;   // ~1 write / 2929 elems
        if (i == n_clb - 1)
            for (int b = cbin + 1; b <= NBINS; ++b) eb[b] = n_clb;
        pbin = cbin;
    }
}

// ---- K2: per-bin mark -> disjoint global bitmap slice ----------------------
__global__ __launch_bounds__(BLOCK) void mark_kernel(
    const int* __restrict__ sig, const int* __restrict__ a2s,
    const int* __restrict__ eb, unsigned int* __restrict__ bm, int n_clb)
{
    __shared__ unsigned int lbm[WORDS_PER_BIN];

    const int g        = blockIdx.x;
    const int siteBase = g * SITES_PER_BIN;
    const int siteEnd  = siteBase + SITES_PER_BIN;

    if (threadIdx.x < WORDS_PER_BIN) lbm[threadIdx.x] = 0u;
    const int e0 = eb[g], e1 = eb[g + 1];
    __syncthreads();

    // 8 entries/thread (4 NT vec4 loads in flight). Strays outside the bin's
    // site range fail the range check (they belong to neighbor bins).
    const int mstart = e0 & ~3;
    for (int s = mstart + threadIdx.x * 8; s < e1; s += BLOCK * 8) {
        int av[8], gv[8];
        if (s + 8 <= n_clb) {
            v4i a0 = __builtin_nontemporal_load((const v4i*)(a2s + s));
            v4i a1 = __builtin_nontemporal_load((const v4i*)(a2s + s + 4));
            v4i g0 = __builtin_nontemporal_load((const v4i*)(sig + s));
            v4i g1 = __builtin_nontemporal_load((const v4i*)(sig + s + 4));
            av[0]=a0.x; av[1]=a0.y; av[2]=a0.z; av[3]=a0.w;
            av[4]=a1.x; av[5]=a1.y; av[6]=a1.z; av[7]=a1.w;
            gv[0]=g0.x; gv[1]=g0.y; gv[2]=g0.z; gv[3]=g0.w;
            gv[4]=g1.x; gv[5]=g1.y; gv[6]=g1.z; gv[7]=g1.w;
        } else {
#pragma unroll
            for (int j = 0; j < 8; ++j) {
                const int i = s + j;
                const bool ok = i < n_clb;
                av[j] = ok ? a2s[i] : -1;
                gv[j] = ok ? sig[i] : 0;
            }
        }
        unsigned int curw = 0xFFFFFFFFu, curm = 0u;
#pragma unroll
        for (int j = 0; j < 8; ++j) {
            const int site = av[j];
            if (gv[j] > 0 && site >= siteBase && site < siteEnd) {
                const unsigned int u = (unsigned int)(site - siteBase);
                const unsigned int w = u >> 5;
                const unsigned int m = 1u << (u & 31u);
                if (w == curw) curm |= m;
                else { if (curm) atomicOr(&lbm[curw], curm); curw = w; curm = m; }
            }
        }
        if (curm) atomicOr(&lbm[curw], curm);
    }

    __syncthreads();

    // Disjoint 512 B slice -> regular stores (keep it cache-resident for K3).
    if (threadIdx.x < WORDS_PER_BIN / 4)
        ((v4i*)(bm + g * WORDS_PER_BIN))[threadIdx.x] =
            ((const v4i*)lbm)[threadIdx.x];
}

// ---- K3: index-partitioned probe ------------------------------------------
__global__ __launch_bounds__(BLOCK) void probe_kernel(
    const int* __restrict__ ss, const float* __restrict__ sc,
    const unsigned int* __restrict__ bm,
    float* __restrict__ rem, float* __restrict__ avail, int n4)
{
    const int q = blockIdx.x * BLOCK + threadIdx.x;
    if (q >= n4) return;
    v4i s = __builtin_nontemporal_load((const v4i*)ss + q);
    v4f f = __builtin_nontemporal_load((const v4f*)sc + q);
    v4f r, a;
#pragma unroll
    for (int j = 0; j < 4; ++j) {
        const unsigned int u   = (unsigned int)s[j];
        const unsigned int bit = (bm[u >> 5] >> (u & 31u)) & 1u;
        r[j] = bit ? 0.0f : 1.0f;
        a[j] = bit ? 0.0f : f[j];
    }
    __builtin_nontemporal_store(r, (v4f*)rem + q);
    __builtin_nontemporal_store(a, (v4f*)avail + q);
}

__global__ void probe_tail_kernel(
    const int* __restrict__ ss, const float* __restrict__ sc,
    const unsigned int* __restrict__ bm,
    float* __restrict__ rem, float* __restrict__ avail, int start, int n)
{
    const int i = start + blockIdx.x * blockDim.x + threadIdx.x;
    if (i >= n) return;
    const unsigned int u   = (unsigned int)ss[i];
    const unsigned int bit = (bm[u >> 5] >> (u & 31u)) & 1u;
    rem[i]   = bit ? 0.0f : 1.0f;
    avail[i] = bit ? 0.0f : sc[i];
}

extern "C" void kernel_launch(void* const* d_in, const int* in_sizes, int n_in,
                              void* d_out, int out_size, void* d_ws, size_t ws_size,
                              hipStream_t stream) {
    const int*   ss  = (const int*)d_in[0];
    const int*   sig = (const int*)d_in[1];
    const int*   a2s = (const int*)d_in[2];
    const float* sc  = (const float*)d_in[3];
    const int n_slice = in_sizes[0];
    const int n_clb   = in_sizes[1];

    unsigned int* bm = (unsigned int*)d_ws;                 // 1 MiB bitmap
    int*          eb = (int*)(bm + NBINS * WORDS_PER_BIN);  // 2049 ints

    // K1: boundaries of a2s (24 MB streaming scan)
    const int t1 = (n_clb / 4 + BLOCK - 1) / BLOCK + 1;
    bounds_kernel<<<t1, BLOCK, 0, stream>>>(a2s, eb, n_clb);

    // K2: per-bin mark -> global bitmap (disjoint stores, full coverage)
    mark_kernel<<<NBINS, BLOCK, 0, stream>>>(sig, a2s, eb, bm, n_clb);

    // K3: index-partitioned probe -> outputs
    float* rem   = (float*)d_out;
    float* avail = rem + n_slice;
    const int n4 = n_slice / 4;
    if (n4 > 0)
        probe_kernel<<<(n4 + BLOCK - 1) / BLOCK, BLOCK, 0, stream>>>(
            ss, sc, bm, rem, avail, n4);
    if (n4 * 4 < n_slice)
        probe_tail_kernel<<<1, 64, 0, stream>>>(ss, sc, bm, rem, avail,
                                                n4 * 4, n_slice);
}